// Round 8
// baseline (84.245 us; speedup 1.0000x reference)
//
#include <hip/hip_runtime.h>

#define NODES  28
#define PPN    320              // points per node
#define MID    13               // (NODES-2)/2
#define NPTS   (NODES * PPN)    // 8960
#define TOTPTS (2 * NPTS)       // 17920
#define SIGMA  10.0f
#define FLT_BIG 3.4e38f

#define BT    64                // threads per pair block (1 wave)
#define RPT   5                 // source points per thread
#define GPTS  (BT * RPT)        // 320 source points per block
#define NGRP  (NPTS / GPTS)     // 28 source groups per direction
#define HALF  2                 // db halves per node
#define DBH   (PPN / HALF)      // 160 db points per block

// ---------------------------------------------------------------------------
// Phase 1: one 1-wave block per (direction p, src-group g, db-node b,
// half h). 160-pt db half clipped+packed into LDS as (-2x,-2y,-2z,|x|^2);
// each thread owns 5 clipped source points in regs (one ds_read_b128
// broadcast feeds 5*64 distances). Composite of all measured-good pieces:
// plain coalesced stores (R3-validated publish), 3136 waves = 3.06/SIMD
// (R3-class occupancy), RPT=5 LDS amortization. Block 0 also zeroes out[]
// (kernel-boundary release orders it before combine's atomics).
// ---------------------------------------------------------------------------
__global__ __launch_bounds__(BT, 4)
void pair_min_kernel(const float* __restrict__ X, const float* __restrict__ T,
                     float* __restrict__ m,     // [HALF][NODES][TOTPTS]
                     float* __restrict__ out)
{
    __shared__ float4 st[DBH];

    const int bid = blockIdx.x;                       // 0 .. 3135
    const int p   = bid / (NGRP * NODES * HALF);      // direction
    const int r1  = bid % (NGRP * NODES * HALF);
    const int g   = r1 / (NODES * HALF);              // source group (320 pts)
    const int r2  = r1 % (NODES * HALF);
    const int b   = r2 / HALF;                        // db node
    const int h   = r2 % HALF;                        // db half

    const float* __restrict__ src = p ? T : X;
    const float* __restrict__ db  = p ? X : T;

    const int t = threadIdx.x;
    if (bid == 0 && t == 0) out[0] = 0.0f;

    // stage + clip + pack db half (160 pts)
    for (int j = t; j < DBH; j += BT) {
        const float* q = db + (size_t)(b * PPN + h * DBH + j) * 3;
        float v0 = fminf(fmaxf(q[0], -SIGMA), SIGMA);
        float v1 = fminf(fmaxf(q[1], -SIGMA), SIGMA);
        float v2 = fminf(fmaxf(q[2], -SIGMA), SIGMA);
        float n  = v0*v0 + v1*v1 + v2*v2;
        st[j] = make_float4(-2.f*v0, -2.f*v1, -2.f*v2, n);
    }

    // own source points (clip + norm), 5 per thread
    float4 sp[RPT];
    #pragma unroll
    for (int k = 0; k < RPT; ++k) {
        const float* q = src + (size_t)(g * GPTS + k * BT + t) * 3;
        float a0 = fminf(fmaxf(q[0], -SIGMA), SIGMA);
        float a1 = fminf(fmaxf(q[1], -SIGMA), SIGMA);
        float a2 = fminf(fmaxf(q[2], -SIGMA), SIGMA);
        sp[k] = make_float4(a0, a1, a2, a0*a0 + a1*a1 + a2*a2);
    }
    __syncthreads();

    float mn[RPT];
    #pragma unroll
    for (int k = 0; k < RPT; ++k) mn[k] = FLT_BIG;

    #pragma unroll 2
    for (int j = 0; j < DBH; j += 2) {
        const float4 ta = st[j];
        const float4 tb = st[j + 1];
        #pragma unroll
        for (int k = 0; k < RPT; ++k) {
            float da  = fmaf(ta.x, sp[k].x, fmaf(ta.y, sp[k].y, fmaf(ta.z, sp[k].z, ta.w)));
            float dbv = fmaf(tb.x, sp[k].x, fmaf(tb.y, sp[k].y, fmaf(tb.z, sp[k].z, tb.w)));
            mn[k] = fminf(mn[k], fminf(da, dbv));   // -> v_min3_f32
        }
    }

    // plain coalesced publish: m[h][b][q]
    float* row = m + ((size_t)h * NODES + b) * TOTPTS
                   + (size_t)p * NPTS + (size_t)g * GPTS;
    #pragma unroll
    for (int k = 0; k < RPT; ++k)
        row[k * BT + t] = mn[k] + sp[k].w;
}

__inline__ __device__ float wave_reduce_sum(float v) {
    #pragma unroll
    for (int off = 32; off > 0; off >>= 1)
        v += __shfl_down(v, off, 64);
    return v;
}

// ---------------------------------------------------------------------------
// Phase 2: per point, fold the 2 half partials (56 coalesced scalar loads),
// then the 26-subset closed form + half-arch term; block-reduce to scalar.
// ---------------------------------------------------------------------------
__global__ __launch_bounds__(256)
void combine_kernel(const float* __restrict__ m,   // [HALF][NODES][TOTPTS]
                    float* __restrict__ out)
{
    const int q = blockIdx.x * blockDim.x + threadIdx.x;  // 0 .. TOTPTS-1
    float tot = 0.0f;
    if (q < TOTPTS) {
        const int a = (q % NPTS) / PPN;   // node of this point

        float r[NODES];
        #pragma unroll
        for (int c = 0; c < NODES; ++c) {
            float v0 = m[(size_t)c * TOTPTS + q];
            float v1 = m[((size_t)NODES + c) * TOTPTS + q];
            r[c] = fminf(v0, v1);
        }

        // min1 / argmin
        float min1 = FLT_BIG; int c1 = -1;
        #pragma unroll
        for (int c = 0; c < NODES; ++c) {
            if (r[c] < min1) { min1 = r[c]; c1 = c; }
        }
        // min over c != c1
        float min2 = FLT_BIG;
        #pragma unroll
        for (int c = 0; c < NODES; ++c) {
            float v = (c == c1) ? FLT_BIG : r[c];
            min2 = fminf(min2, v);
        }
        // half-arch min
        float H = FLT_BIG;
        if (a < MID) {
            #pragma unroll
            for (int c = 0; c < MID; ++c) H = fminf(H, r[c]);
        } else {
            #pragma unroll
            for (int c = MID; c < NODES; ++c) H = fminf(H, r[c]);
        }

        const int n = (a < NODES - 2) ? (NODES - 3) : (NODES - 2); // 25 or 26
        float S = (float)n * min1;
        if (c1 <= NODES - 3 && c1 != a) S -= (min1 - min2);
        if (a < NODES - 2) {
            const int dup = (a < MID) ? (a + MID) : (a - MID);
            S += (c1 == dup) ? min2 : min1;
        }
        tot = S + H;
    }

    __shared__ float warp_sums[4];
    float ws = wave_reduce_sum(tot);
    const int lane = threadIdx.x & 63;
    const int wid  = threadIdx.x >> 6;
    if (lane == 0) warp_sums[wid] = ws;
    __syncthreads();
    if (wid == 0) {
        float v = (lane < 4) ? warp_sums[lane] : 0.0f;
        v = wave_reduce_sum(v);
        if (lane == 0) atomicAdd(out, v);
    }
}

extern "C" void kernel_launch(void* const* d_in, const int* in_sizes, int n_in,
                              void* d_out, int out_size, void* d_ws, size_t ws_size,
                              hipStream_t stream) {
    const float* X = (const float*)d_in[0];
    const float* T = (const float*)d_in[1];
    float* out = (float*)d_out;
    float* m   = (float*)d_ws;               // [HALF][NODES][TOTPTS] = 4.0 MB

    pair_min_kernel<<<2 * NGRP * NODES * HALF, BT, 0, stream>>>(X, T, m, out);
    combine_kernel<<<TOTPTS / 256, 256, 0, stream>>>(m, out);
}